// Round 1
// baseline (7229.807 us; speedup 1.0000x reference)
//
#include <hip/hip_runtime.h>

#define N_NODES 50000
#define N_GRAPHS 512
#define N_EDGES 800000

// ---------------- zero fill (ws is poisoned 0xAA each call) ----------------
__global__ void zero_kernel(float* __restrict__ p, int n_floats) {
    int i = blockIdx.x * blockDim.x + threadIdx.x;
    if (4 * i < n_floats) ((float4*)p)[i] = make_float4(0.f, 0.f, 0.f, 0.f);
}

// ---------------- edge scatter: agg[dst] += h[src] -------------------------
// C channels per node; each thread handles 4 channels (float4 gather + 4 atomics).
template <int C>
__global__ void edge_scatter(const float* __restrict__ h, float* __restrict__ agg,
                             const int* __restrict__ src, const int* __restrict__ dst) {
    const int PER = C / 4;  // threads per edge
    int t = blockIdx.x * blockDim.x + threadIdx.x;
    int e = t / PER;
    int cg = t % PER;
    if (e >= N_EDGES) return;
    int s = src[e];
    int d = dst[e];
    float4 v = ((const float4*)(h + (long long)s * C))[cg];
    float* out = agg + (long long)d * C + cg * 4;
    atomicAdd(out + 0, v.x);
    atomicAdd(out + 1, v.y);
    atomicAdd(out + 2, v.z);
    atomicAdd(out + 3, v.w);
}

// ---------------- GEMM: C = relu((A1+A2) @ W^T + b) -------------------------
// A1,A2: [M,K] row-major (summed on load: agg + self), W: [N,K] row-major,
// C: [M,N]. BM=BN=64, BK=16, 256 threads, 4x4 micro-tile per thread.
__global__ __launch_bounds__(256) void gemm_relu(
    const float* __restrict__ A1, const float* __restrict__ A2,
    const float* __restrict__ W, const float* __restrict__ bias,
    float* __restrict__ C, int M, int N, int K) {
    const int BM = 64, BN = 64, BK = 16;
    __shared__ float As[BK][BM + 4];  // K-major, +4 pad keeps 16B align & breaks conflicts
    __shared__ float Ws[BK][BN + 4];

    int tid = threadIdx.x;
    int rowbase = blockIdx.x * BM;
    int colbase = blockIdx.y * BN;
    int lm = tid & 63;        // element within tile edge for loading
    int lk = (tid >> 6) * 4;  // k sub-offset: 0,4,8,12
    int ty = tid >> 4;        // 0..15 -> rows 4*ty..4*ty+3
    int tx = tid & 15;        // 0..15 -> cols 4*tx..4*tx+3

    float acc[4][4] = {};

    for (int k0 = 0; k0 < K; k0 += BK) {
        int arow = rowbase + lm;
        if (arow >= M) arow = M - 1;  // clamp; results for OOB rows discarded at store
        float4 a1 = *(const float4*)(A1 + (long long)arow * K + k0 + lk);
        float4 a2 = *(const float4*)(A2 + (long long)arow * K + k0 + lk);
        As[lk + 0][lm] = a1.x + a2.x;
        As[lk + 1][lm] = a1.y + a2.y;
        As[lk + 2][lm] = a1.z + a2.z;
        As[lk + 3][lm] = a1.w + a2.w;
        float4 w4 = *(const float4*)(W + (long long)(colbase + lm) * K + k0 + lk);
        Ws[lk + 0][lm] = w4.x;
        Ws[lk + 1][lm] = w4.y;
        Ws[lk + 2][lm] = w4.z;
        Ws[lk + 3][lm] = w4.w;
        __syncthreads();

#pragma unroll
        for (int kk = 0; kk < BK; kk++) {
            float4 av = *(const float4*)&As[kk][4 * ty];
            float4 wv = *(const float4*)&Ws[kk][4 * tx];
            acc[0][0] += av.x * wv.x; acc[0][1] += av.x * wv.y;
            acc[0][2] += av.x * wv.z; acc[0][3] += av.x * wv.w;
            acc[1][0] += av.y * wv.x; acc[1][1] += av.y * wv.y;
            acc[1][2] += av.y * wv.z; acc[1][3] += av.y * wv.w;
            acc[2][0] += av.z * wv.x; acc[2][1] += av.z * wv.y;
            acc[2][2] += av.z * wv.z; acc[2][3] += av.z * wv.w;
            acc[3][0] += av.w * wv.x; acc[3][1] += av.w * wv.y;
            acc[3][2] += av.w * wv.z; acc[3][3] += av.w * wv.w;
        }
        __syncthreads();
    }

#pragma unroll
    for (int i = 0; i < 4; i++) {
        int r = rowbase + 4 * ty + i;
        if (r >= M) continue;
#pragma unroll
        for (int j = 0; j < 4; j++) {
            int c = colbase + 4 * tx + j;
            float v = acc[i][j] + bias[c];
            C[(long long)r * N + c] = fmaxf(v, 0.f);
        }
    }
}

// ---------------- mean-pool accumulate ------------------------------------
__global__ void pool_kernel(const float* __restrict__ h, const int* __restrict__ batch,
                            float* __restrict__ sums, float* __restrict__ cnts) {
    int t = blockIdx.x * blockDim.x + threadIdx.x;
    if (t >= N_NODES * 256) return;
    int n = t >> 8;
    int c = t & 255;
    int g = batch[n];
    atomicAdd(&sums[g * 256 + c], h[t]);
    if (c == 0) atomicAdd(&cnts[g], 1.0f);
}

// ---------------- MLP head: one block per graph ----------------------------
__global__ __launch_bounds__(128) void head_kernel(
    const float* __restrict__ sums, const float* __restrict__ cnts,
    const float* __restrict__ Wf1, const float* __restrict__ bf1,
    const float* __restrict__ Wf2, const float* __restrict__ bf2,
    float* __restrict__ out) {
    __shared__ float hg[256];
    __shared__ float hid[128];
    int g = blockIdx.x;
    int t = threadIdx.x;
    float inv = 1.0f / fmaxf(cnts[g], 1.0f);
    hg[t] = sums[g * 256 + t] * inv;
    hg[t + 128] = sums[g * 256 + t + 128] * inv;
    __syncthreads();
    float acc = bf1[t];
    for (int c = 0; c < 256; c++) acc += hg[c] * Wf1[t * 256 + c];
    hid[t] = fmaxf(acc, 0.f);
    __syncthreads();
    if (t < 10) {
        float a = bf2[t];
        for (int j = 0; j < 128; j++) a += hid[j] * Wf2[t * 128 + j];
        out[g * 10 + t] = a;
    }
}

extern "C" void kernel_launch(void* const* d_in, const int* in_sizes, int n_in,
                              void* d_out, int out_size, void* d_ws, size_t ws_size,
                              hipStream_t stream) {
    const float* x   = (const float*)d_in[0];
    const int*  edge = (const int*)d_in[1];   // [2][800000]: row0=src, row1=dst
    const int*  batch= (const int*)d_in[2];
    const float* W1  = (const float*)d_in[3];
    const float* b1  = (const float*)d_in[4];
    const float* W2  = (const float*)d_in[5];
    const float* b2  = (const float*)d_in[6];
    const float* W3  = (const float*)d_in[7];
    const float* b3  = (const float*)d_in[8];
    const float* Wf1 = (const float*)d_in[9];
    const float* bf1 = (const float*)d_in[10];
    const float* Wf2 = (const float*)d_in[11];
    const float* bf2 = (const float*)d_in[12];
    const int* src = edge;
    const int* dst = edge + N_EDGES;

    float* ws   = (float*)d_ws;
    float* agg  = ws;                    // 50000*256 floats (layer1 uses first 50000*128)
    float* hA   = ws + 12800000;         // 50000*256
    float* hB   = ws + 25600000;         // 50000*256
    float* sums = ws + 38400000;         // 512*256
    float* cnts = sums + 131072;         // 512

    dim3 ggrid(782, 4);  // ceil(50000/64), 256/64

    // ---- layer 1 (K=128) ----
    zero_kernel<<<(50000 * 128 / 4 + 255) / 256, 256, 0, stream>>>(agg, 50000 * 128);
    edge_scatter<128><<<(N_EDGES * 32 + 255) / 256, 256, 0, stream>>>(x, agg, src, dst);
    gemm_relu<<<ggrid, 256, 0, stream>>>(agg, x, W1, b1, hA, N_NODES, 256, 128);

    // ---- layer 2 (K=256) ----
    zero_kernel<<<(12800000 / 4 + 255) / 256, 256, 0, stream>>>(agg, 12800000);
    edge_scatter<256><<<(N_EDGES * 64 + 255) / 256, 256, 0, stream>>>(hA, agg, src, dst);
    gemm_relu<<<ggrid, 256, 0, stream>>>(agg, hA, W2, b2, hB, N_NODES, 256, 256);

    // ---- layer 3 (K=256) ----
    zero_kernel<<<(12800000 / 4 + 255) / 256, 256, 0, stream>>>(agg, 12800000);
    edge_scatter<256><<<(N_EDGES * 64 + 255) / 256, 256, 0, stream>>>(hB, agg, src, dst);
    gemm_relu<<<ggrid, 256, 0, stream>>>(agg, hB, W3, b3, hA, N_NODES, 256, 256);

    // ---- mean pool + head ----
    zero_kernel<<<(131584 / 4 + 255) / 256, 256, 0, stream>>>(sums, 131584);  // sums+cnts
    pool_kernel<<<(N_NODES * 256 + 255) / 256, 256, 0, stream>>>(hA, batch, sums, cnts);
    head_kernel<<<N_GRAPHS, 128, 0, stream>>>(sums, cnts, Wf1, bf1, Wf2, bf2, (float*)d_out);
}

// Round 2
// 770.532 us; speedup vs baseline: 9.3829x; 9.3829x over previous
//
#include <hip/hip_runtime.h>

#define N_NODES 50000
#define N_GRAPHS 512
#define N_EDGES 800000

// ---------------- zero fill ----------------
__global__ void zero_kernel(float* __restrict__ p, int n_floats) {
    int i = blockIdx.x * blockDim.x + threadIdx.x;
    if (4 * i < n_floats) ((float4*)p)[i] = make_float4(0.f, 0.f, 0.f, 0.f);
}

// ---------------- CSR build ----------------
__global__ void deg_hist(const int* __restrict__ dst, int* __restrict__ deg) {
    int e = blockIdx.x * blockDim.x + threadIdx.x;
    if (e < N_EDGES) atomicAdd(&deg[dst[e]], 1);
}

// inclusive block scan (1024/block) -> exclusive per-block rowptr + block sums
__global__ __launch_bounds__(1024) void scan1(const int* __restrict__ deg,
                                              int* __restrict__ rowptr,
                                              int* __restrict__ blocksum) {
    __shared__ int s[1024];
    int t = threadIdx.x;
    int i = blockIdx.x * 1024 + t;
    int v = (i < N_NODES) ? deg[i] : 0;
    s[t] = v;
    __syncthreads();
    for (int off = 1; off < 1024; off <<= 1) {
        int add = (t >= off) ? s[t - off] : 0;
        __syncthreads();
        s[t] += add;
        __syncthreads();
    }
    if (i < N_NODES) rowptr[i] = s[t] - v;  // exclusive
    if (t == 1023) blocksum[blockIdx.x] = s[t];
}

__global__ void scan2(int* __restrict__ blocksum, int nb) {
    if (threadIdx.x == 0 && blockIdx.x == 0) {
        int run = 0;
        for (int i = 0; i < nb; i++) { int v = blocksum[i]; blocksum[i] = run; run += v; }
    }
}

__global__ void scan3(int* __restrict__ rowptr, const int* __restrict__ blocksum,
                      int* __restrict__ cursor) {
    int i = blockIdx.x * blockDim.x + threadIdx.x;
    if (i < N_NODES) {
        int v = rowptr[i] + blocksum[i >> 10];
        rowptr[i] = v;
        cursor[i] = v;
    }
    if (i == 0) rowptr[N_NODES] = N_EDGES;
}

__global__ void scatter_csr(const int* __restrict__ src, const int* __restrict__ dst,
                            int* __restrict__ cursor, int* __restrict__ csr) {
    int e = blockIdx.x * blockDim.x + threadIdx.x;
    if (e < N_EDGES) {
        int pos = atomicAdd(&cursor[dst[e]], 1);
        csr[pos] = src[e];
    }
}

// ---------------- aggregation gather: agg[n] = h[n] + sum_{j in N(n)} h[j] ----
template <int C>
__global__ __launch_bounds__(256) void gather_agg(const float* __restrict__ h,
                                                  const int* __restrict__ rowptr,
                                                  const int* __restrict__ csr,
                                                  float* __restrict__ agg) {
    const int TPN = C / 4;        // threads per node (float4 each)
    const int NPB = 256 / TPN;    // nodes per block
    int t = threadIdx.x;
    int n = blockIdx.x * NPB + t / TPN;
    if (n >= N_NODES) return;
    int c4 = t % TPN;
    const float4* hp = (const float4*)h;
    float4 acc = hp[(long long)n * TPN + c4];  // self term
    int beg = rowptr[n], end = rowptr[n + 1];
    for (int p = beg; p < end; ++p) {
        int j = csr[p];
        float4 v = hp[(long long)j * TPN + c4];
        acc.x += v.x; acc.y += v.y; acc.z += v.z; acc.w += v.w;
    }
    ((float4*)agg)[(long long)n * TPN + c4] = acc;
}

// ---------------- GEMM: C = relu(A @ W^T + b) ------------------------------
__global__ __launch_bounds__(256) void gemm_relu(
    const float* __restrict__ A, const float* __restrict__ W,
    const float* __restrict__ bias, float* __restrict__ C, int M, int N, int K) {
    const int BM = 64, BN = 64, BK = 16;
    __shared__ float As[BK][BM + 4];
    __shared__ float Ws[BK][BN + 4];

    int tid = threadIdx.x;
    int rowbase = blockIdx.x * BM;
    int colbase = blockIdx.y * BN;
    int lm = tid & 63;
    int lk = (tid >> 6) * 4;
    int ty = tid >> 4;
    int tx = tid & 15;

    float acc[4][4] = {};

    for (int k0 = 0; k0 < K; k0 += BK) {
        int arow = rowbase + lm;
        if (arow >= M) arow = M - 1;
        float4 a = *(const float4*)(A + (long long)arow * K + k0 + lk);
        As[lk + 0][lm] = a.x;
        As[lk + 1][lm] = a.y;
        As[lk + 2][lm] = a.z;
        As[lk + 3][lm] = a.w;
        float4 w4 = *(const float4*)(W + (long long)(colbase + lm) * K + k0 + lk);
        Ws[lk + 0][lm] = w4.x;
        Ws[lk + 1][lm] = w4.y;
        Ws[lk + 2][lm] = w4.z;
        Ws[lk + 3][lm] = w4.w;
        __syncthreads();

#pragma unroll
        for (int kk = 0; kk < BK; kk++) {
            float4 av = *(const float4*)&As[kk][4 * ty];
            float4 wv = *(const float4*)&Ws[kk][4 * tx];
            acc[0][0] += av.x * wv.x; acc[0][1] += av.x * wv.y;
            acc[0][2] += av.x * wv.z; acc[0][3] += av.x * wv.w;
            acc[1][0] += av.y * wv.x; acc[1][1] += av.y * wv.y;
            acc[1][2] += av.y * wv.z; acc[1][3] += av.y * wv.w;
            acc[2][0] += av.z * wv.x; acc[2][1] += av.z * wv.y;
            acc[2][2] += av.z * wv.z; acc[2][3] += av.z * wv.w;
            acc[3][0] += av.w * wv.x; acc[3][1] += av.w * wv.y;
            acc[3][2] += av.w * wv.z; acc[3][3] += av.w * wv.w;
        }
        __syncthreads();
    }

#pragma unroll
    for (int i = 0; i < 4; i++) {
        int r = rowbase + 4 * ty + i;
        if (r >= M) continue;
#pragma unroll
        for (int j = 0; j < 4; j++) {
            int c = colbase + 4 * tx + j;
            float v = acc[i][j] + bias[c];
            C[(long long)r * N + c] = fmaxf(v, 0.f);
        }
    }
}

// ---------------- mean pool: one block per graph, batch is sorted ----------
__global__ __launch_bounds__(256) void pool_mean(const float* __restrict__ h,
                                                 const int* __restrict__ batch,
                                                 float* __restrict__ hg) {
    int g = blockIdx.x;
    int t = threadIdx.x;
    // lower_bound(batch, g) and lower_bound(batch, g+1), computed redundantly
    int lo = 0, hi = N_NODES;
    while (lo < hi) { int m = (lo + hi) >> 1; if (batch[m] < g) lo = m + 1; else hi = m; }
    int start = lo;
    lo = 0; hi = N_NODES;
    while (lo < hi) { int m = (lo + hi) >> 1; if (batch[m] < g + 1) lo = m + 1; else hi = m; }
    int end = lo;
    float acc = 0.f;
    for (int r = start; r < end; ++r) acc += h[(long long)r * 256 + t];
    float inv = 1.0f / fmaxf((float)(end - start), 1.0f);
    hg[g * 256 + t] = acc * inv;
}

// ---------------- MLP head: one block per graph ----------------------------
__global__ __launch_bounds__(128) void head_kernel(
    const float* __restrict__ hg_in,
    const float* __restrict__ Wf1, const float* __restrict__ bf1,
    const float* __restrict__ Wf2, const float* __restrict__ bf2,
    float* __restrict__ out) {
    __shared__ float hg[256];
    __shared__ float hid[128];
    int g = blockIdx.x;
    int t = threadIdx.x;
    hg[t] = hg_in[g * 256 + t];
    hg[t + 128] = hg_in[g * 256 + t + 128];
    __syncthreads();
    float acc = bf1[t];
    for (int c = 0; c < 256; c++) acc += hg[c] * Wf1[t * 256 + c];
    hid[t] = fmaxf(acc, 0.f);
    __syncthreads();
    if (t < 10) {
        float a = bf2[t];
        for (int j = 0; j < 128; j++) a += hid[j] * Wf2[t * 128 + j];
        out[g * 10 + t] = a;
    }
}

extern "C" void kernel_launch(void* const* d_in, const int* in_sizes, int n_in,
                              void* d_out, int out_size, void* d_ws, size_t ws_size,
                              hipStream_t stream) {
    const float* x   = (const float*)d_in[0];
    const int*  edge = (const int*)d_in[1];
    const int*  batch= (const int*)d_in[2];
    const float* W1  = (const float*)d_in[3];
    const float* b1  = (const float*)d_in[4];
    const float* W2  = (const float*)d_in[5];
    const float* b2  = (const float*)d_in[6];
    const float* W3  = (const float*)d_in[7];
    const float* b3  = (const float*)d_in[8];
    const float* Wf1 = (const float*)d_in[9];
    const float* bf1 = (const float*)d_in[10];
    const float* Wf2 = (const float*)d_in[11];
    const float* bf2 = (const float*)d_in[12];
    const int* src = edge;
    const int* dst = edge + N_EDGES;

    float* ws  = (float*)d_ws;
    float* agg = ws;                 // 50000*256
    float* hA  = ws + 12800000;      // 50000*256
    float* hB  = ws + 25600000;      // 50000*256
    float* hg  = ws + 38400000;      // 512*256
    int* ip      = (int*)(ws + 38531072);
    int* rowptr  = ip;               // 50001 (pad to 50004)
    int* cursor  = ip + 50004;       // 50000
    int* deg     = ip + 100008;      // 50000
    int* csr     = ip + 150012;      // 800000
    int* blocksum= ip + 950012;      // 49

    const int NB_SCAN = (N_NODES + 1023) / 1024;  // 49

    // ---- CSR build (by dst) ----
    zero_kernel<<<(N_NODES / 4 + 255) / 256, 256, 0, stream>>>((float*)deg, N_NODES);
    deg_hist<<<(N_EDGES + 255) / 256, 256, 0, stream>>>(dst, deg);
    scan1<<<NB_SCAN, 1024, 0, stream>>>(deg, rowptr, blocksum);
    scan2<<<1, 64, 0, stream>>>(blocksum, NB_SCAN);
    scan3<<<NB_SCAN, 1024, 0, stream>>>(rowptr, blocksum, cursor);
    scatter_csr<<<(N_EDGES + 255) / 256, 256, 0, stream>>>(src, dst, cursor, csr);

    dim3 ggrid(782, 4);  // ceil(50000/64) x 256/64

    // ---- layer 1 (K=128) ----
    gather_agg<128><<<(N_NODES + 7) / 8, 256, 0, stream>>>(x, rowptr, csr, agg);
    gemm_relu<<<ggrid, 256, 0, stream>>>(agg, W1, b1, hA, N_NODES, 256, 128);

    // ---- layer 2 (K=256) ----
    gather_agg<256><<<(N_NODES + 3) / 4, 256, 0, stream>>>(hA, rowptr, csr, agg);
    gemm_relu<<<ggrid, 256, 0, stream>>>(agg, W2, b2, hB, N_NODES, 256, 256);

    // ---- layer 3 (K=256) ----
    gather_agg<256><<<(N_NODES + 3) / 4, 256, 0, stream>>>(hB, rowptr, csr, agg);
    gemm_relu<<<ggrid, 256, 0, stream>>>(agg, W3, b3, hA, N_NODES, 256, 256);

    // ---- mean pool + head ----
    pool_mean<<<N_GRAPHS, 256, 0, stream>>>(hA, batch, hg);
    head_kernel<<<N_GRAPHS, 128, 0, stream>>>(hg, Wf1, bf1, Wf2, bf2, (float*)d_out);
}

// Round 3
// 523.827 us; speedup vs baseline: 13.8019x; 1.4710x over previous
//
#include <hip/hip_runtime.h>

#define N_NODES 50000
#define N_GRAPHS 512
#define N_EDGES 800000

typedef __attribute__((ext_vector_type(8))) short short8;
typedef __attribute__((ext_vector_type(8))) unsigned short ushort8;
typedef __attribute__((ext_vector_type(4))) float floatx4;

__device__ __forceinline__ float bf2f(unsigned short u) {
    union { unsigned int i; float f; } c;
    c.i = ((unsigned int)u) << 16;
    return c.f;
}
__device__ __forceinline__ unsigned short f2bf(float f) {
    union { float f; unsigned int i; } c;
    c.f = f;
    unsigned int u = c.i;
    return (unsigned short)((u + 0x7fffu + ((u >> 16) & 1u)) >> 16);
}

// ---------------- zero fill ----------------
__global__ void zero_kernel(float* __restrict__ p, int n_floats) {
    int i = blockIdx.x * blockDim.x + threadIdx.x;
    if (4 * i < n_floats) ((float4*)p)[i] = make_float4(0.f, 0.f, 0.f, 0.f);
}

// ---------------- f32 -> bf16 convert ----------------
__global__ void convert_bf16(const float* __restrict__ in, unsigned short* __restrict__ out, int n) {
    int i = blockIdx.x * blockDim.x + threadIdx.x;
    if (i < n) out[i] = f2bf(in[i]);
}

// ---------------- CSR build ----------------
__global__ void deg_hist(const int* __restrict__ dst, int* __restrict__ deg) {
    int e = blockIdx.x * blockDim.x + threadIdx.x;
    if (e < N_EDGES) atomicAdd(&deg[dst[e]], 1);
}

__global__ __launch_bounds__(1024) void scan1(const int* __restrict__ deg,
                                              int* __restrict__ rowptr,
                                              int* __restrict__ blocksum) {
    __shared__ int s[1024];
    int t = threadIdx.x;
    int i = blockIdx.x * 1024 + t;
    int v = (i < N_NODES) ? deg[i] : 0;
    s[t] = v;
    __syncthreads();
    for (int off = 1; off < 1024; off <<= 1) {
        int add = (t >= off) ? s[t - off] : 0;
        __syncthreads();
        s[t] += add;
        __syncthreads();
    }
    if (i < N_NODES) rowptr[i] = s[t] - v;  // exclusive
    if (t == 1023) blocksum[blockIdx.x] = s[t];
}

__global__ void scan2(int* __restrict__ blocksum, int nb) {
    if (threadIdx.x == 0 && blockIdx.x == 0) {
        int run = 0;
        for (int i = 0; i < nb; i++) { int v = blocksum[i]; blocksum[i] = run; run += v; }
    }
}

__global__ void scan3(int* __restrict__ rowptr, const int* __restrict__ blocksum,
                      int* __restrict__ cursor) {
    int i = blockIdx.x * blockDim.x + threadIdx.x;
    if (i < N_NODES) {
        int v = rowptr[i] + blocksum[i >> 10];
        rowptr[i] = v;
        cursor[i] = v;
    }
    if (i == 0) rowptr[N_NODES] = N_EDGES;
}

__global__ void scatter_csr(const int* __restrict__ src, const int* __restrict__ dst,
                            int* __restrict__ cursor, int* __restrict__ csr) {
    int e = blockIdx.x * blockDim.x + threadIdx.x;
    if (e < N_EDGES) {
        int pos = atomicAdd(&cursor[dst[e]], 1);
        csr[pos] = src[e];
    }
}

// ---- bf16 gather: agg[n] = h[n] + sum_{j in N(n)} h[j], fp32 accumulate ----
template <int C>
__global__ __launch_bounds__(256) void gather_bf(const unsigned short* __restrict__ h,
                                                 const int* __restrict__ rowptr,
                                                 const int* __restrict__ csr,
                                                 unsigned short* __restrict__ agg) {
    const int TPN = C / 8;       // threads per node, ushort8 (16B) each
    const int NPB = 256 / TPN;   // nodes per block
    int t = threadIdx.x;
    int n = blockIdx.x * NPB + t / TPN;
    if (n >= N_NODES) return;
    int c8 = t % TPN;
    const ushort8* hp = (const ushort8*)h;
    ushort8 s = hp[n * TPN + c8];
    float acc[8];
#pragma unroll
    for (int j = 0; j < 8; j++) acc[j] = bf2f(s[j]);
    int beg = rowptr[n], end = rowptr[n + 1];
    for (int p = beg; p < end; ++p) {
        int nb = csr[p];
        ushort8 v = hp[nb * TPN + c8];
#pragma unroll
        for (int j = 0; j < 8; j++) acc[j] += bf2f(v[j]);
    }
    ushort8 o;
#pragma unroll
    for (int j = 0; j < 8; j++) o[j] = f2bf(acc[j]);
    ((ushort8*)agg)[n * TPN + c8] = o;
}

// ---- MFMA GEMM: out = relu(A[M,K]bf16 @ W[256,K]bf16^T + b), N=256 --------
// BM=128, BN=128 (blockIdx.y in {0,1}), BK=32, 256 threads = 4 waves (2x2).
// LDS fragment-order layout [mtile][slot] with slot = kc*16 + (r ^ (kc<<2)).
__global__ __launch_bounds__(256) void gemm_mfma(
    const unsigned short* __restrict__ A, const unsigned short* __restrict__ W,
    const float* __restrict__ bias, unsigned short* __restrict__ Cbf,
    float* __restrict__ Cf, int M, int K) {
    const int BM = 128, BK = 32;
    __shared__ short8 As[8 * 64];
    __shared__ short8 Ws[8 * 64];

    int tid = threadIdx.x;
    int wave = tid >> 6, lane = tid & 63;
    int wm = wave & 1, wn = wave >> 1;
    int rowbase = blockIdx.x * BM;
    int colbase = blockIdx.y * 128;
    int lkc = lane >> 4, lr = lane & 15;
    int rslot = lkc * 16 + (lr ^ (lkc << 2));

    floatx4 acc[4][4];
#pragma unroll
    for (int i = 0; i < 4; i++)
#pragma unroll
        for (int j = 0; j < 4; j++) acc[i][j] = (floatx4)(0.f);

    for (int k0 = 0; k0 < K; k0 += BK) {
#pragma unroll
        for (int i = 0; i < 2; i++) {
            int idx = i * 256 + tid;
            int row = idx >> 2, kc = idx & 3;
            int slot = (row >> 4) * 64 + kc * 16 + ((row & 15) ^ (kc << 2));
            int ar = rowbase + row;
            if (ar >= M) ar = M - 1;
            As[slot] = *(const short8*)(A + (size_t)ar * K + k0 + kc * 8);
            Ws[slot] = *(const short8*)(W + (size_t)(colbase + row) * K + k0 + kc * 8);
        }
        __syncthreads();

        short8 af[4], wf[4];
#pragma unroll
        for (int mt = 0; mt < 4; mt++) af[mt] = As[(wm * 4 + mt) * 64 + rslot];
#pragma unroll
        for (int nt = 0; nt < 4; nt++) wf[nt] = Ws[(wn * 4 + nt) * 64 + rslot];
#pragma unroll
        for (int mt = 0; mt < 4; mt++)
#pragma unroll
            for (int nt = 0; nt < 4; nt++)
                acc[mt][nt] = __builtin_amdgcn_mfma_f32_16x16x32_bf16(
                    af[mt], wf[nt], acc[mt][nt], 0, 0, 0);
        __syncthreads();
    }

    // epilogue: C/D layout col=lane&15, row=(lane>>4)*4+reg  [verified m89/m91]
    int ccol = lane & 15;
    int r0 = (lane >> 4) * 4;
#pragma unroll
    for (int mt = 0; mt < 4; mt++) {
#pragma unroll
        for (int reg = 0; reg < 4; reg++) {
            int row = rowbase + (wm * 4 + mt) * 16 + r0 + reg;
            if (row >= M) continue;
#pragma unroll
            for (int nt = 0; nt < 4; nt++) {
                int col = colbase + (wn * 4 + nt) * 16 + ccol;
                float v = acc[mt][nt][reg] + bias[col];
                v = fmaxf(v, 0.f);
                if (Cbf) Cbf[(size_t)row * 256 + col] = f2bf(v);
                if (Cf) Cf[(size_t)row * 256 + col] = v;
            }
        }
    }
}

// ---------------- mean pool: one block per graph, batch sorted -------------
__global__ __launch_bounds__(256) void pool_mean(const float* __restrict__ h,
                                                 const int* __restrict__ batch,
                                                 float* __restrict__ hg) {
    int g = blockIdx.x;
    int t = threadIdx.x;
    int lo = 0, hi = N_NODES;
    while (lo < hi) { int m = (lo + hi) >> 1; if (batch[m] < g) lo = m + 1; else hi = m; }
    int start = lo;
    lo = 0; hi = N_NODES;
    while (lo < hi) { int m = (lo + hi) >> 1; if (batch[m] < g + 1) lo = m + 1; else hi = m; }
    int end = lo;
    float acc = 0.f;
    for (int r = start; r < end; ++r) acc += h[(size_t)r * 256 + t];
    float inv = 1.0f / fmaxf((float)(end - start), 1.0f);
    hg[g * 256 + t] = acc * inv;
}

// ---------------- MLP head ----------------
__global__ __launch_bounds__(128) void head_kernel(
    const float* __restrict__ hg_in,
    const float* __restrict__ Wf1, const float* __restrict__ bf1,
    const float* __restrict__ Wf2, const float* __restrict__ bf2,
    float* __restrict__ out) {
    __shared__ float hg[256];
    __shared__ float hid[128];
    int g = blockIdx.x;
    int t = threadIdx.x;
    hg[t] = hg_in[g * 256 + t];
    hg[t + 128] = hg_in[g * 256 + t + 128];
    __syncthreads();
    float acc = bf1[t];
    for (int c = 0; c < 256; c++) acc += hg[c] * Wf1[t * 256 + c];
    hid[t] = fmaxf(acc, 0.f);
    __syncthreads();
    if (t < 10) {
        float a = bf2[t];
        for (int j = 0; j < 128; j++) a += hid[j] * Wf2[t * 128 + j];
        out[g * 10 + t] = a;
    }
}

extern "C" void kernel_launch(void* const* d_in, const int* in_sizes, int n_in,
                              void* d_out, int out_size, void* d_ws, size_t ws_size,
                              hipStream_t stream) {
    const float* x   = (const float*)d_in[0];
    const int*  edge = (const int*)d_in[1];
    const int*  batch= (const int*)d_in[2];
    const float* W1  = (const float*)d_in[3];
    const float* b1  = (const float*)d_in[4];
    const float* W2  = (const float*)d_in[5];
    const float* b2  = (const float*)d_in[6];
    const float* W3  = (const float*)d_in[7];
    const float* b3  = (const float*)d_in[8];
    const float* Wf1 = (const float*)d_in[9];
    const float* bf1 = (const float*)d_in[10];
    const float* Wf2 = (const float*)d_in[11];
    const float* bf2 = (const float*)d_in[12];
    const int* src = edge;
    const int* dst = edge + N_EDGES;

    char* wsb = (char*)d_ws;
    size_t off = 0;
    auto alloc = [&](size_t bytes) { void* p = wsb + off; off += (bytes + 255) & ~(size_t)255; return p; };
    unsigned short* x_bf  = (unsigned short*)alloc((size_t)N_NODES * 128 * 2);
    unsigned short* agg_bf= (unsigned short*)alloc((size_t)N_NODES * 256 * 2);
    unsigned short* hA_bf = (unsigned short*)alloc((size_t)N_NODES * 256 * 2);
    unsigned short* hB_bf = (unsigned short*)alloc((size_t)N_NODES * 256 * 2);
    float*          h3f   = (float*)alloc((size_t)N_NODES * 256 * 4);
    unsigned short* W1bf  = (unsigned short*)alloc(256 * 128 * 2);
    unsigned short* W2bf  = (unsigned short*)alloc(256 * 256 * 2);
    unsigned short* W3bf  = (unsigned short*)alloc(256 * 256 * 2);
    float*          hg    = (float*)alloc(N_GRAPHS * 256 * 4);
    int* rowptr   = (int*)alloc((N_NODES + 4) * 4);
    int* cursor   = (int*)alloc(N_NODES * 4);
    int* deg      = (int*)alloc(N_NODES * 4);
    int* csr      = (int*)alloc(N_EDGES * 4);
    int* blocksum = (int*)alloc(64 * 4);

    const int NB_SCAN = (N_NODES + 1023) / 1024;  // 49

    // ---- CSR build (by dst) ----
    zero_kernel<<<(N_NODES / 4 + 255) / 256, 256, 0, stream>>>((float*)deg, N_NODES);
    deg_hist<<<(N_EDGES + 255) / 256, 256, 0, stream>>>(dst, deg);
    scan1<<<NB_SCAN, 1024, 0, stream>>>(deg, rowptr, blocksum);
    scan2<<<1, 64, 0, stream>>>(blocksum, NB_SCAN);
    scan3<<<NB_SCAN, 1024, 0, stream>>>(rowptr, blocksum, cursor);
    scatter_csr<<<(N_EDGES + 255) / 256, 256, 0, stream>>>(src, dst, cursor, csr);

    // ---- converts ----
    convert_bf16<<<(N_NODES * 128 + 255) / 256, 256, 0, stream>>>(x, x_bf, N_NODES * 128);
    convert_bf16<<<(256 * 128 + 255) / 256, 256, 0, stream>>>(W1, W1bf, 256 * 128);
    convert_bf16<<<(256 * 256 + 255) / 256, 256, 0, stream>>>(W2, W2bf, 256 * 256);
    convert_bf16<<<(256 * 256 + 255) / 256, 256, 0, stream>>>(W3, W3bf, 256 * 256);

    dim3 ggrid((N_NODES + 127) / 128, 2);  // 391 x 2

    // ---- layer 1 (K=128) ----
    gather_bf<128><<<(N_NODES + 15) / 16, 256, 0, stream>>>(x_bf, rowptr, csr, agg_bf);
    gemm_mfma<<<ggrid, 256, 0, stream>>>(agg_bf, W1bf, b1, hA_bf, nullptr, N_NODES, 128);

    // ---- layer 2 (K=256) ----
    gather_bf<256><<<(N_NODES + 7) / 8, 256, 0, stream>>>(hA_bf, rowptr, csr, agg_bf);
    gemm_mfma<<<ggrid, 256, 0, stream>>>(agg_bf, W2bf, b2, hB_bf, nullptr, N_NODES, 256);

    // ---- layer 3 (K=256), fp32 out for pool/head ----
    gather_bf<256><<<(N_NODES + 7) / 8, 256, 0, stream>>>(hB_bf, rowptr, csr, agg_bf);
    gemm_mfma<<<ggrid, 256, 0, stream>>>(agg_bf, W3bf, b3, nullptr, h3f, N_NODES, 256);

    // ---- mean pool + head (fp32) ----
    pool_mean<<<N_GRAPHS, 256, 0, stream>>>(h3f, batch, hg);
    head_kernel<<<N_GRAPHS, 128, 0, stream>>>(hg, Wf1, bf1, Wf2, bf2, (float*)d_out);
}

// Round 4
// 522.106 us; speedup vs baseline: 13.8474x; 1.0033x over previous
//
#include <hip/hip_runtime.h>

#define N_NODES 50000
#define N_GRAPHS 512
#define N_EDGES 800000

typedef __attribute__((ext_vector_type(8))) short short8;
typedef __attribute__((ext_vector_type(8))) unsigned short ushort8;
typedef __attribute__((ext_vector_type(4))) float floatx4;

__device__ __forceinline__ float bf2f(unsigned short u) {
    union { unsigned int i; float f; } c;
    c.i = ((unsigned int)u) << 16;
    return c.f;
}
__device__ __forceinline__ unsigned short f2bf(float f) {
    union { float f; unsigned int i; } c;
    c.f = f;
    unsigned int u = c.i;
    return (unsigned short)((u + 0x7fffu + ((u >> 16) & 1u)) >> 16);
}

// ---------------- zero fill ----------------
__global__ void zero_kernel(int* __restrict__ p, int n) {
    int i = blockIdx.x * blockDim.x + threadIdx.x;
    if (i < n) p[i] = 0;
}

// ---------------- converts ----------------
__global__ void convert_x4(const float* __restrict__ in, unsigned short* __restrict__ out, int n4) {
    int i = blockIdx.x * blockDim.x + threadIdx.x;
    if (i >= n4) return;
    float4 v = ((const float4*)in)[i];
    ushort4 o;
    o.x = f2bf(v.x); o.y = f2bf(v.y); o.z = f2bf(v.z); o.w = f2bf(v.w);
    ((ushort4*)out)[i] = o;
}

// all three weight matrices in one launch (float4 granules)
__global__ void convert_w(const float* __restrict__ W1, const float* __restrict__ W2,
                          const float* __restrict__ W3, unsigned short* __restrict__ o1,
                          unsigned short* __restrict__ o2, unsigned short* __restrict__ o3) {
    int i = blockIdx.x * blockDim.x + threadIdx.x;  // 0..40959
    const float* src; unsigned short* dst; int base;
    if (i < 8192)        { src = W1; dst = o1; base = i; }
    else if (i < 24576)  { src = W2; dst = o2; base = i - 8192; }
    else if (i < 40960)  { src = W3; dst = o3; base = i - 24576; }
    else return;
    float4 v = ((const float4*)src)[base];
    ushort4 o;
    o.x = f2bf(v.x); o.y = f2bf(v.y); o.z = f2bf(v.z); o.w = f2bf(v.w);
    ((ushort4*)dst)[base] = o;
}

// ---------------- CSR build ----------------
__global__ void deg_hist(const int* __restrict__ dst, int* __restrict__ deg) {
    int e = blockIdx.x * blockDim.x + threadIdx.x;
    if (e < N_EDGES) atomicAdd(&deg[dst[e]], 1);
}

// single-block scan: 1024 threads x 49 elements each
__global__ __launch_bounds__(1024) void scan_all(const int* __restrict__ deg,
                                                 int* __restrict__ rowptr,
                                                 int* __restrict__ cursor) {
    const int PER = 49;
    __shared__ int s[1024];
    int t = threadIdx.x;
    int base = t * PER;
    int loc[PER];
    int sum = 0;
#pragma unroll
    for (int i = 0; i < PER; i++) {
        int idx = base + i;
        int v = (idx < N_NODES) ? deg[idx] : 0;
        loc[i] = v;
        sum += v;
    }
    s[t] = sum;
    __syncthreads();
    for (int off = 1; off < 1024; off <<= 1) {
        int add = (t >= off) ? s[t - off] : 0;
        __syncthreads();
        s[t] += add;
        __syncthreads();
    }
    int run = s[t] - sum;  // exclusive prefix of this chunk
#pragma unroll
    for (int i = 0; i < PER; i++) {
        int idx = base + i;
        if (idx < N_NODES) { rowptr[idx] = run; cursor[idx] = run; }
        run += loc[i];
    }
    if (t == 0) rowptr[N_NODES] = N_EDGES;
}

__global__ void scatter_csr(const int* __restrict__ src, const int* __restrict__ dst,
                            int* __restrict__ cursor, int* __restrict__ csr) {
    int e = blockIdx.x * blockDim.x + threadIdx.x;
    if (e < N_EDGES) {
        int pos = atomicAdd(&cursor[dst[e]], 1);
        csr[pos] = src[e];
    }
}

// ---- bf16 gather, unroll-4 for MLP: agg[n] = h[n] + sum_{j in N(n)} h[j] ----
template <int C>
__global__ __launch_bounds__(256) void gather_bf(const unsigned short* __restrict__ h,
                                                 const int* __restrict__ rowptr,
                                                 const int* __restrict__ csr,
                                                 unsigned short* __restrict__ agg) {
    const int TPN = C / 8;       // lanes per node (ushort8 = 16B each)
    const int NPB = 256 / TPN;
    int t = threadIdx.x;
    int n = blockIdx.x * NPB + t / TPN;
    if (n >= N_NODES) return;
    int c8 = t % TPN;
    const ushort8* hp = (const ushort8*)h + c8;
    ushort8 s = hp[(size_t)n * TPN];
    float acc[8];
#pragma unroll
    for (int j = 0; j < 8; j++) acc[j] = bf2f(s[j]);
    int p = rowptr[n], end = rowptr[n + 1];
    for (; p + 4 <= end; p += 4) {
        int j0 = csr[p], j1 = csr[p + 1], j2 = csr[p + 2], j3 = csr[p + 3];
        ushort8 v0 = hp[(size_t)j0 * TPN];
        ushort8 v1 = hp[(size_t)j1 * TPN];
        ushort8 v2 = hp[(size_t)j2 * TPN];
        ushort8 v3 = hp[(size_t)j3 * TPN];
#pragma unroll
        for (int j = 0; j < 8; j++)
            acc[j] += (bf2f(v0[j]) + bf2f(v1[j])) + (bf2f(v2[j]) + bf2f(v3[j]));
    }
    for (; p < end; ++p) {
        int jj = csr[p];
        ushort8 v = hp[(size_t)jj * TPN];
#pragma unroll
        for (int j = 0; j < 8; j++) acc[j] += bf2f(v[j]);
    }
    ushort8 o;
#pragma unroll
    for (int j = 0; j < 8; j++) o[j] = f2bf(acc[j]);
    ((ushort8*)agg)[(size_t)n * TPN + c8] = o;
}

// ---- MFMA GEMM: out = relu(A[M,K]bf16 @ W[256,K]bf16^T + b) -> bf16 -------
// BM=128, BN=128 (blockIdx.y in {0,1}), BK=32, 256 threads = 4 waves (2x2).
__global__ __launch_bounds__(256) void gemm_mfma(
    const unsigned short* __restrict__ A, const unsigned short* __restrict__ W,
    const float* __restrict__ bias, unsigned short* __restrict__ Cbf, int M, int K) {
    const int BM = 128, BK = 32;
    __shared__ short8 As[8 * 64];
    __shared__ short8 Ws[8 * 64];

    int tid = threadIdx.x;
    int wave = tid >> 6, lane = tid & 63;
    int wm = wave & 1, wn = wave >> 1;
    int rowbase = blockIdx.x * BM;
    int colbase = blockIdx.y * 128;
    int lkc = lane >> 4, lr = lane & 15;
    int rslot = lkc * 16 + (lr ^ (lkc << 2));

    floatx4 acc[4][4];
#pragma unroll
    for (int i = 0; i < 4; i++)
#pragma unroll
        for (int j = 0; j < 4; j++) acc[i][j] = (floatx4)(0.f);

    for (int k0 = 0; k0 < K; k0 += BK) {
#pragma unroll
        for (int i = 0; i < 2; i++) {
            int idx = i * 256 + tid;
            int row = idx >> 2, kc = idx & 3;
            int slot = (row >> 4) * 64 + kc * 16 + ((row & 15) ^ (kc << 2));
            int ar = rowbase + row;
            if (ar >= M) ar = M - 1;
            As[slot] = *(const short8*)(A + (size_t)ar * K + k0 + kc * 8);
            Ws[slot] = *(const short8*)(W + (size_t)(colbase + row) * K + k0 + kc * 8);
        }
        __syncthreads();

        short8 af[4], wf[4];
#pragma unroll
        for (int mt = 0; mt < 4; mt++) af[mt] = As[(wm * 4 + mt) * 64 + rslot];
#pragma unroll
        for (int nt = 0; nt < 4; nt++) wf[nt] = Ws[(wn * 4 + nt) * 64 + rslot];
#pragma unroll
        for (int mt = 0; mt < 4; mt++)
#pragma unroll
            for (int nt = 0; nt < 4; nt++)
                acc[mt][nt] = __builtin_amdgcn_mfma_f32_16x16x32_bf16(
                    af[mt], wf[nt], acc[mt][nt], 0, 0, 0);
        __syncthreads();
    }

    // C/D layout: col=lane&15, row=(lane>>4)*4+reg
    int ccol = lane & 15;
    int r0 = (lane >> 4) * 4;
#pragma unroll
    for (int mt = 0; mt < 4; mt++) {
#pragma unroll
        for (int reg = 0; reg < 4; reg++) {
            int row = rowbase + (wm * 4 + mt) * 16 + r0 + reg;
            if (row >= M) continue;
#pragma unroll
            for (int nt = 0; nt < 4; nt++) {
                int col = colbase + (wn * 4 + nt) * 16 + ccol;
                float v = acc[mt][nt][reg] + bias[col];
                Cbf[(size_t)row * 256 + col] = f2bf(fmaxf(v, 0.f));
            }
        }
    }
}

// ---------------- mean pool (bf16 in, fp32 out), batch sorted --------------
__global__ __launch_bounds__(256) void pool_mean(const unsigned short* __restrict__ h,
                                                 const int* __restrict__ batch,
                                                 float* __restrict__ hg) {
    int g = blockIdx.x;
    int t = threadIdx.x;
    int lo = 0, hi = N_NODES;
    while (lo < hi) { int m = (lo + hi) >> 1; if (batch[m] < g) lo = m + 1; else hi = m; }
    int start = lo;
    lo = 0; hi = N_NODES;
    while (lo < hi) { int m = (lo + hi) >> 1; if (batch[m] < g + 1) lo = m + 1; else hi = m; }
    int end = lo;
    float acc = 0.f;
    for (int r = start; r < end; ++r) acc += bf2f(h[(size_t)r * 256 + t]);
    float inv = 1.0f / fmaxf((float)(end - start), 1.0f);
    hg[g * 256 + t] = acc * inv;
}

// ---------------- MLP head ----------------
__global__ __launch_bounds__(128) void head_kernel(
    const float* __restrict__ hg_in,
    const float* __restrict__ Wf1, const float* __restrict__ bf1,
    const float* __restrict__ Wf2, const float* __restrict__ bf2,
    float* __restrict__ out) {
    __shared__ float hg[256];
    __shared__ float hid[128];
    int g = blockIdx.x;
    int t = threadIdx.x;
    hg[t] = hg_in[g * 256 + t];
    hg[t + 128] = hg_in[g * 256 + t + 128];
    __syncthreads();
    float acc = bf1[t];
    for (int c = 0; c < 256; c++) acc += hg[c] * Wf1[t * 256 + c];
    hid[t] = fmaxf(acc, 0.f);
    __syncthreads();
    if (t < 10) {
        float a = bf2[t];
        for (int j = 0; j < 128; j++) a += hid[j] * Wf2[t * 128 + j];
        out[g * 10 + t] = a;
    }
}

extern "C" void kernel_launch(void* const* d_in, const int* in_sizes, int n_in,
                              void* d_out, int out_size, void* d_ws, size_t ws_size,
                              hipStream_t stream) {
    const float* x   = (const float*)d_in[0];
    const int*  edge = (const int*)d_in[1];
    const int*  batch= (const int*)d_in[2];
    const float* W1  = (const float*)d_in[3];
    const float* b1  = (const float*)d_in[4];
    const float* W2  = (const float*)d_in[5];
    const float* b2  = (const float*)d_in[6];
    const float* W3  = (const float*)d_in[7];
    const float* b3  = (const float*)d_in[8];
    const float* Wf1 = (const float*)d_in[9];
    const float* bf1 = (const float*)d_in[10];
    const float* Wf2 = (const float*)d_in[11];
    const float* bf2 = (const float*)d_in[12];
    const int* src = edge;
    const int* dst = edge + N_EDGES;

    char* wsb = (char*)d_ws;
    size_t off = 0;
    auto alloc = [&](size_t bytes) { void* p = wsb + off; off += (bytes + 255) & ~(size_t)255; return p; };
    unsigned short* x_bf  = (unsigned short*)alloc((size_t)N_NODES * 128 * 2);
    unsigned short* agg_bf= (unsigned short*)alloc((size_t)N_NODES * 256 * 2);
    unsigned short* hA_bf = (unsigned short*)alloc((size_t)N_NODES * 256 * 2);
    unsigned short* hB_bf = (unsigned short*)alloc((size_t)N_NODES * 256 * 2);
    unsigned short* W1bf  = (unsigned short*)alloc(256 * 128 * 2);
    unsigned short* W2bf  = (unsigned short*)alloc(256 * 256 * 2);
    unsigned short* W3bf  = (unsigned short*)alloc(256 * 256 * 2);
    float*          hg    = (float*)alloc(N_GRAPHS * 256 * 4);
    int* rowptr   = (int*)alloc((N_NODES + 4) * 4);
    int* cursor   = (int*)alloc(N_NODES * 4);
    int* deg      = (int*)alloc(N_NODES * 4);
    int* csr      = (int*)alloc(N_EDGES * 4);

    // ---- CSR build (by dst) ----
    zero_kernel<<<(N_NODES + 255) / 256, 256, 0, stream>>>(deg, N_NODES);
    deg_hist<<<(N_EDGES + 255) / 256, 256, 0, stream>>>(dst, deg);
    scan_all<<<1, 1024, 0, stream>>>(deg, rowptr, cursor);
    scatter_csr<<<(N_EDGES + 255) / 256, 256, 0, stream>>>(src, dst, cursor, csr);

    // ---- converts (vectorized) ----
    convert_x4<<<(N_NODES * 128 / 4 + 255) / 256, 256, 0, stream>>>(x, x_bf, N_NODES * 128 / 4);
    convert_w<<<(40960 + 255) / 256, 256, 0, stream>>>(W1, W2, W3, W1bf, W2bf, W3bf);

    dim3 ggrid((N_NODES + 127) / 128, 2);  // 391 x 2

    // ---- layer 1 (K=128) ----
    gather_bf<128><<<(N_NODES + 15) / 16, 256, 0, stream>>>(x_bf, rowptr, csr, agg_bf);
    gemm_mfma<<<ggrid, 256, 0, stream>>>(agg_bf, W1bf, b1, hA_bf, N_NODES, 128);

    // ---- layer 2 (K=256) ----
    gather_bf<256><<<(N_NODES + 7) / 8, 256, 0, stream>>>(hA_bf, rowptr, csr, agg_bf);
    gemm_mfma<<<ggrid, 256, 0, stream>>>(agg_bf, W2bf, b2, hB_bf, N_NODES, 256);

    // ---- layer 3 (K=256), bf16 out reusing hA ----
    gather_bf<256><<<(N_NODES + 7) / 8, 256, 0, stream>>>(hB_bf, rowptr, csr, agg_bf);
    gemm_mfma<<<ggrid, 256, 0, stream>>>(agg_bf, W3bf, b3, hA_bf, N_NODES, 256);

    // ---- mean pool + head ----
    pool_mean<<<N_GRAPHS, 256, 0, stream>>>(hA_bf, batch, hg);
    head_kernel<<<N_GRAPHS, 128, 0, stream>>>(hg, Wf1, bf1, Wf2, bf2, (float*)d_out);
}

// Round 5
// 459.985 us; speedup vs baseline: 15.7175x; 1.1351x over previous
//
#include <hip/hip_runtime.h>

#define N_NODES 50000
#define N_GRAPHS 512
#define N_EDGES 800000

typedef __attribute__((ext_vector_type(8))) short short8;
typedef __attribute__((ext_vector_type(8))) unsigned short ushort8;
typedef __attribute__((ext_vector_type(4))) float floatx4;

__device__ __forceinline__ float bf2f(unsigned short u) {
    union { unsigned int i; float f; } c;
    c.i = ((unsigned int)u) << 16;
    return c.f;
}
__device__ __forceinline__ unsigned short f2bf(float f) {
    union { float f; unsigned int i; } c;
    c.f = f;
    unsigned int u = c.i;
    return (unsigned short)((u + 0x7fffu + ((u >> 16) & 1u)) >> 16);
}

// ---------------- zero fill ----------------
__global__ void zero_kernel(int* __restrict__ p, int n) {
    int i = blockIdx.x * blockDim.x + threadIdx.x;
    if (i < n) p[i] = 0;
}

// ---------------- converts ----------------
__global__ void convert_x4(const float* __restrict__ in, unsigned short* __restrict__ out, int n4) {
    int i = blockIdx.x * blockDim.x + threadIdx.x;
    if (i >= n4) return;
    float4 v = ((const float4*)in)[i];
    ushort4 o;
    o.x = f2bf(v.x); o.y = f2bf(v.y); o.z = f2bf(v.z); o.w = f2bf(v.w);
    ((ushort4*)out)[i] = o;
}

__global__ void convert_w(const float* __restrict__ W1, const float* __restrict__ W2,
                          const float* __restrict__ W3, unsigned short* __restrict__ o1,
                          unsigned short* __restrict__ o2, unsigned short* __restrict__ o3) {
    int i = blockIdx.x * blockDim.x + threadIdx.x;  // 0..40959
    const float* src; unsigned short* dst; int base;
    if (i < 8192)        { src = W1; dst = o1; base = i; }
    else if (i < 24576)  { src = W2; dst = o2; base = i - 8192; }
    else if (i < 40960)  { src = W3; dst = o3; base = i - 24576; }
    else return;
    float4 v = ((const float4*)src)[base];
    ushort4 o;
    o.x = f2bf(v.x); o.y = f2bf(v.y); o.z = f2bf(v.z); o.w = f2bf(v.w);
    ((ushort4*)dst)[base] = o;
}

// ---------------- CSR build ----------------
__global__ void deg_hist(const int* __restrict__ dst, int* __restrict__ deg) {
    int e = blockIdx.x * blockDim.x + threadIdx.x;
    if (e < N_EDGES) atomicAdd(&deg[dst[e]], 1);
}

// hierarchical scan: 49 blocks x 1024 (proven ~10us total in R2/R3)
__global__ __launch_bounds__(1024) void scan1(const int* __restrict__ deg,
                                              int* __restrict__ rowptr,
                                              int* __restrict__ blocksum) {
    __shared__ int s[1024];
    int t = threadIdx.x;
    int i = blockIdx.x * 1024 + t;
    int v = (i < N_NODES) ? deg[i] : 0;
    s[t] = v;
    __syncthreads();
    for (int off = 1; off < 1024; off <<= 1) {
        int add = (t >= off) ? s[t - off] : 0;
        __syncthreads();
        s[t] += add;
        __syncthreads();
    }
    if (i < N_NODES) rowptr[i] = s[t] - v;  // exclusive
    if (t == 1023) blocksum[blockIdx.x] = s[t];
}

__global__ void scan2(int* __restrict__ blocksum, int nb) {
    if (threadIdx.x == 0 && blockIdx.x == 0) {
        int run = 0;
        for (int i = 0; i < nb; i++) { int v = blocksum[i]; blocksum[i] = run; run += v; }
    }
}

__global__ void scan3(int* __restrict__ rowptr, const int* __restrict__ blocksum,
                      int* __restrict__ cursor) {
    int i = blockIdx.x * blockDim.x + threadIdx.x;
    if (i < N_NODES) {
        int v = rowptr[i] + blocksum[i >> 10];
        rowptr[i] = v;
        cursor[i] = v;
    }
    if (i == 0) rowptr[N_NODES] = N_EDGES;
}

__global__ void scatter_csr(const int* __restrict__ src, const int* __restrict__ dst,
                            int* __restrict__ cursor, int* __restrict__ csr) {
    int e = blockIdx.x * blockDim.x + threadIdx.x;
    if (e < N_EDGES) {
        int pos = atomicAdd(&cursor[dst[e]], 1);
        csr[pos] = src[e];
    }
}

// ---- bf16 gather, unroll-4 MLP: agg[n] = h[n] + sum_{j in N(n)} h[j] ------
template <int C>
__global__ __launch_bounds__(256) void gather_bf(const unsigned short* __restrict__ h,
                                                 const int* __restrict__ rowptr,
                                                 const int* __restrict__ csr,
                                                 unsigned short* __restrict__ agg) {
    const int TPN = C / 8;       // lanes per node (ushort8 = 16B each)
    const int NPB = 256 / TPN;
    int t = threadIdx.x;
    int n = blockIdx.x * NPB + t / TPN;
    if (n >= N_NODES) return;
    int c8 = t % TPN;
    const ushort8* hp = (const ushort8*)h + c8;
    ushort8 s = hp[(size_t)n * TPN];
    float acc[8];
#pragma unroll
    for (int j = 0; j < 8; j++) acc[j] = bf2f(s[j]);
    int p = rowptr[n], end = rowptr[n + 1];
    for (; p + 4 <= end; p += 4) {
        int j0 = csr[p], j1 = csr[p + 1], j2 = csr[p + 2], j3 = csr[p + 3];
        ushort8 v0 = hp[(size_t)j0 * TPN];
        ushort8 v1 = hp[(size_t)j1 * TPN];
        ushort8 v2 = hp[(size_t)j2 * TPN];
        ushort8 v3 = hp[(size_t)j3 * TPN];
#pragma unroll
        for (int j = 0; j < 8; j++)
            acc[j] += (bf2f(v0[j]) + bf2f(v1[j])) + (bf2f(v2[j]) + bf2f(v3[j]));
    }
    for (; p < end; ++p) {
        int jj = csr[p];
        ushort8 v = hp[(size_t)jj * TPN];
#pragma unroll
        for (int j = 0; j < 8; j++) acc[j] += bf2f(v[j]);
    }
    ushort8 o;
#pragma unroll
    for (int j = 0; j < 8; j++) o[j] = f2bf(acc[j]);
    ((ushort8*)agg)[(size_t)n * TPN + c8] = o;
}

// ---- MFMA GEMM: out = relu(A[M,K]bf16 @ W[256,K]bf16^T + b) -> bf16 -------
__global__ __launch_bounds__(256) void gemm_mfma(
    const unsigned short* __restrict__ A, const unsigned short* __restrict__ W,
    const float* __restrict__ bias, unsigned short* __restrict__ Cbf, int M, int K) {
    const int BM = 128, BK = 32;
    __shared__ short8 As[8 * 64];
    __shared__ short8 Ws[8 * 64];

    int tid = threadIdx.x;
    int wave = tid >> 6, lane = tid & 63;
    int wm = wave & 1, wn = wave >> 1;
    int rowbase = blockIdx.x * BM;
    int colbase = blockIdx.y * 128;
    int lkc = lane >> 4, lr = lane & 15;
    int rslot = lkc * 16 + (lr ^ (lkc << 2));

    floatx4 acc[4][4];
#pragma unroll
    for (int i = 0; i < 4; i++)
#pragma unroll
        for (int j = 0; j < 4; j++) acc[i][j] = (floatx4)(0.f);

    for (int k0 = 0; k0 < K; k0 += BK) {
#pragma unroll
        for (int i = 0; i < 2; i++) {
            int idx = i * 256 + tid;
            int row = idx >> 2, kc = idx & 3;
            int slot = (row >> 4) * 64 + kc * 16 + ((row & 15) ^ (kc << 2));
            int ar = rowbase + row;
            if (ar >= M) ar = M - 1;
            As[slot] = *(const short8*)(A + (size_t)ar * K + k0 + kc * 8);
            Ws[slot] = *(const short8*)(W + (size_t)(colbase + row) * K + k0 + kc * 8);
        }
        __syncthreads();

        short8 af[4], wf[4];
#pragma unroll
        for (int mt = 0; mt < 4; mt++) af[mt] = As[(wm * 4 + mt) * 64 + rslot];
#pragma unroll
        for (int nt = 0; nt < 4; nt++) wf[nt] = Ws[(wn * 4 + nt) * 64 + rslot];
#pragma unroll
        for (int mt = 0; mt < 4; mt++)
#pragma unroll
            for (int nt = 0; nt < 4; nt++)
                acc[mt][nt] = __builtin_amdgcn_mfma_f32_16x16x32_bf16(
                    af[mt], wf[nt], acc[mt][nt], 0, 0, 0);
        __syncthreads();
    }

    int ccol = lane & 15;
    int r0 = (lane >> 4) * 4;
#pragma unroll
    for (int mt = 0; mt < 4; mt++) {
#pragma unroll
        for (int reg = 0; reg < 4; reg++) {
            int row = rowbase + (wm * 4 + mt) * 16 + r0 + reg;
            if (row >= M) continue;
#pragma unroll
            for (int nt = 0; nt < 4; nt++) {
                int col = colbase + (wn * 4 + nt) * 16 + ccol;
                float v = acc[mt][nt][reg] + bias[col];
                Cbf[(size_t)row * 256 + col] = f2bf(fmaxf(v, 0.f));
            }
        }
    }
}

// ---------------- mean pool (bf16 in, fp32 out), batch sorted --------------
__global__ __launch_bounds__(256) void pool_mean(const unsigned short* __restrict__ h,
                                                 const int* __restrict__ batch,
                                                 float* __restrict__ hg) {
    int g = blockIdx.x;
    int t = threadIdx.x;
    int lo = 0, hi = N_NODES;
    while (lo < hi) { int m = (lo + hi) >> 1; if (batch[m] < g) lo = m + 1; else hi = m; }
    int start = lo;
    lo = 0; hi = N_NODES;
    while (lo < hi) { int m = (lo + hi) >> 1; if (batch[m] < g + 1) lo = m + 1; else hi = m; }
    int end = lo;
    float acc = 0.f;
    for (int r = start; r < end; ++r) acc += bf2f(h[(size_t)r * 256 + t]);
    float inv = 1.0f / fmaxf((float)(end - start), 1.0f);
    hg[g * 256 + t] = acc * inv;
}

// ---------------- MLP head ----------------
__global__ __launch_bounds__(128) void head_kernel(
    const float* __restrict__ hg_in,
    const float* __restrict__ Wf1, const float* __restrict__ bf1,
    const float* __restrict__ Wf2, const float* __restrict__ bf2,
    float* __restrict__ out) {
    __shared__ float hg[256];
    __shared__ float hid[128];
    int g = blockIdx.x;
    int t = threadIdx.x;
    hg[t] = hg_in[g * 256 + t];
    hg[t + 128] = hg_in[g * 256 + t + 128];
    __syncthreads();
    float acc = bf1[t];
    for (int c = 0; c < 256; c++) acc += hg[c] * Wf1[t * 256 + c];
    hid[t] = fmaxf(acc, 0.f);
    __syncthreads();
    if (t < 10) {
        float a = bf2[t];
        for (int j = 0; j < 128; j++) a += hid[j] * Wf2[t * 128 + j];
        out[g * 10 + t] = a;
    }
}

extern "C" void kernel_launch(void* const* d_in, const int* in_sizes, int n_in,
                              void* d_out, int out_size, void* d_ws, size_t ws_size,
                              hipStream_t stream) {
    const float* x   = (const float*)d_in[0];
    const int*  edge = (const int*)d_in[1];
    const int*  batch= (const int*)d_in[2];
    const float* W1  = (const float*)d_in[3];
    const float* b1  = (const float*)d_in[4];
    const float* W2  = (const float*)d_in[5];
    const float* b2  = (const float*)d_in[6];
    const float* W3  = (const float*)d_in[7];
    const float* b3  = (const float*)d_in[8];
    const float* Wf1 = (const float*)d_in[9];
    const float* bf1 = (const float*)d_in[10];
    const float* Wf2 = (const float*)d_in[11];
    const float* bf2 = (const float*)d_in[12];
    const int* src = edge;
    const int* dst = edge + N_EDGES;

    char* wsb = (char*)d_ws;
    size_t off = 0;
    auto alloc = [&](size_t bytes) { void* p = wsb + off; off += (bytes + 255) & ~(size_t)255; return p; };
    unsigned short* x_bf  = (unsigned short*)alloc((size_t)N_NODES * 128 * 2);
    unsigned short* agg_bf= (unsigned short*)alloc((size_t)N_NODES * 256 * 2);
    unsigned short* hA_bf = (unsigned short*)alloc((size_t)N_NODES * 256 * 2);
    unsigned short* hB_bf = (unsigned short*)alloc((size_t)N_NODES * 256 * 2);
    unsigned short* W1bf  = (unsigned short*)alloc(256 * 128 * 2);
    unsigned short* W2bf  = (unsigned short*)alloc(256 * 256 * 2);
    unsigned short* W3bf  = (unsigned short*)alloc(256 * 256 * 2);
    float*          hg    = (float*)alloc(N_GRAPHS * 256 * 4);
    int* rowptr   = (int*)alloc((N_NODES + 4) * 4);
    int* cursor   = (int*)alloc(N_NODES * 4);
    int* deg      = (int*)alloc(N_NODES * 4);
    int* csr      = (int*)alloc(N_EDGES * 4);
    int* blocksum = (int*)alloc(64 * 4);

    const int NB_SCAN = (N_NODES + 1023) / 1024;  // 49

    // ---- CSR build (by dst) ----
    zero_kernel<<<(N_NODES + 255) / 256, 256, 0, stream>>>(deg, N_NODES);
    deg_hist<<<(N_EDGES + 255) / 256, 256, 0, stream>>>(dst, deg);
    scan1<<<NB_SCAN, 1024, 0, stream>>>(deg, rowptr, blocksum);
    scan2<<<1, 64, 0, stream>>>(blocksum, NB_SCAN);
    scan3<<<NB_SCAN, 1024, 0, stream>>>(rowptr, blocksum, cursor);
    scatter_csr<<<(N_EDGES + 255) / 256, 256, 0, stream>>>(src, dst, cursor, csr);

    // ---- converts (vectorized) ----
    convert_x4<<<(N_NODES * 128 / 4 + 255) / 256, 256, 0, stream>>>(x, x_bf, N_NODES * 128 / 4);
    convert_w<<<(40960 + 255) / 256, 256, 0, stream>>>(W1, W2, W3, W1bf, W2bf, W3bf);

    dim3 ggrid((N_NODES + 127) / 128, 2);  // 391 x 2

    // ---- layer 1 (K=128) ----
    gather_bf<128><<<(N_NODES + 15) / 16, 256, 0, stream>>>(x_bf, rowptr, csr, agg_bf);
    gemm_mfma<<<ggrid, 256, 0, stream>>>(agg_bf, W1bf, b1, hA_bf, N_NODES, 128);

    // ---- layer 2 (K=256) ----
    gather_bf<256><<<(N_NODES + 7) / 8, 256, 0, stream>>>(hA_bf, rowptr, csr, agg_bf);
    gemm_mfma<<<ggrid, 256, 0, stream>>>(agg_bf, W2bf, b2, hB_bf, N_NODES, 256);

    // ---- layer 3 (K=256), bf16 out reusing hA ----
    gather_bf<256><<<(N_NODES + 7) / 8, 256, 0, stream>>>(hB_bf, rowptr, csr, agg_bf);
    gemm_mfma<<<ggrid, 256, 0, stream>>>(agg_bf, W3bf, b3, hA_bf, N_NODES, 256);

    // ---- mean pool + head ----
    pool_mean<<<N_GRAPHS, 256, 0, stream>>>(hA_bf, batch, hg);
    head_kernel<<<N_GRAPHS, 128, 0, stream>>>(hg, Wf1, bf1, Wf2, bf2, (float*)d_out);
}